// Round 2
// baseline (2199.219 us; speedup 1.0000x reference)
//
#include <hip/hip_runtime.h>
#include <hip/hip_bf16.h>
#include <math.h>

typedef float  f32x4  __attribute__((ext_vector_type(4)));
typedef short  bf16x4 __attribute__((ext_vector_type(4)));
typedef __bf16 bfv4   __attribute__((ext_vector_type(4)));

#define B_    16
#define S_    4096
#define D_    256
#define CK_   16                 // chunk length
#define NC_   (S_ / CK_)         // 256 chunks
#define NP_   (NC_ / 2)          // 128 fused pairs (32-row superchunks)
#define PBLOB_ 1664              // 512 Ta + 512 Tb + 512 Gx (bf16) + 64 ca + 64 cb (f32)
#define W_    8                  // waves per main block (column split)

// ---------------- helpers
__device__ __forceinline__ f32x4 mfma_bf16(bf16x4 a, bf16x4 b, f32x4 c) {
#if defined(__has_builtin) && __has_builtin(__builtin_amdgcn_mfma_f32_16x16x16bf16_1k)
    return __builtin_amdgcn_mfma_f32_16x16x16bf16_1k(a, b, c, 0, 0, 0);
#else
    f32x4 d;
    asm("v_mfma_f32_16x16x16_bf16 %0, %1, %2, %3" : "=v"(d) : "v"(a), "v"(b), "v"(c));
    return d;
#endif
}
__device__ __forceinline__ bf16x4 pk4(f32x4 v) {
    bfv4 h;
    h[0] = (__bf16)v[0]; h[1] = (__bf16)v[1]; h[2] = (__bf16)v[2]; h[3] = (__bf16)v[3];
    return __builtin_bit_cast(bf16x4, h);
}
__device__ __forceinline__ f32x4 up4(bf16x4 h) {
    f32x4 r;
    r[0] = __uint_as_float(((unsigned)(unsigned short)h[0]) << 16);
    r[1] = __uint_as_float(((unsigned)(unsigned short)h[1]) << 16);
    r[2] = __uint_as_float(((unsigned)(unsigned short)h[2]) << 16);
    r[3] = __uint_as_float(((unsigned)(unsigned short)h[3]) << 16);
    return r;
}

// ---------------- prepass: one 256-thread block (4 waves) per (b, pair).
// Wave wv accumulates kb = wv*4..wv*4+3 partials of G_a, G_b, Gx; LDS reduce;
// then coeffs + T fwd-sub exactly as before (tid<32). 8 waves/SIMD occupancy.
__global__ __launch_bounds__(256) void ldm_prep(
    const float* __restrict__ x,
    const float* __restrict__ eta_raw,
    const float* __restrict__ alpha_raw,
    unsigned char* __restrict__ blob)
{
    const int tid  = threadIdx.x;
    const int lane = tid & 63;
    const int wv   = tid >> 6;
    const int b = blockIdx.x >> 7;            // NP_ = 128
    const int p = blockIdx.x & (NP_ - 1);
    const int l15 = lane & 15;
    const int q   = lane >> 4;

    __shared__ float Ga[256], Gb[256], Gxs[256];
    __shared__ float csh[32];
    __shared__ float Ts[2][256];
    __shared__ f32x4 gpart[4][3][64];         // 12 KB partials

    // A-fragments: lane holds row t=l15, cols kb*16 + q*4 + {0..3}
    const float* xa = x + ((size_t)b * S_ + (size_t)p * 32 + l15) * D_ + q * 4;
    const float* xc = xa + 16 * D_;           // chunk b rows

    const f32x4 z = {0,0,0,0};
    f32x4 ga1=z, ga2=z, ga3=z, gb1=z, gb2=z, gb3=z, gx1=z, gx2=z, gx3=z;
    #pragma unroll
    for (int i = 0; i < 4; ++i) {
        const int kb = wv * 4 + i;
        f32x4 va = *(const f32x4*)(xa + kb * 16);
        f32x4 vb = *(const f32x4*)(xc + kb * 16);
        bf16x4 ha = pk4(va), la = pk4(va - up4(ha));
        bf16x4 hb = pk4(vb), lb = pk4(vb - up4(hb));
        ga1 = mfma_bf16(ha, ha, ga1);
        ga2 = mfma_bf16(ha, la, ga2);
        ga3 = mfma_bf16(la, ha, ga3);
        gb1 = mfma_bf16(hb, hb, gb1);
        gb2 = mfma_bf16(hb, lb, gb2);
        gb3 = mfma_bf16(lb, hb, gb3);
        gx1 = mfma_bf16(hb, ha, gx1);         // Gx[t_b][t_a] = x_b . x_a
        gx2 = mfma_bf16(hb, la, gx2);
        gx3 = mfma_bf16(lb, ha, gx3);
    }
    gpart[wv][0][lane] = (ga1 + ga2) + ga3;
    gpart[wv][1][lane] = (gb1 + gb2) + gb3;
    gpart[wv][2][lane] = (gx1 + gx2) + gx3;
    __syncthreads();

    if (tid < 64) {
        f32x4 ga = (gpart[0][0][lane] + gpart[1][0][lane]) + (gpart[2][0][lane] + gpart[3][0][lane]);
        f32x4 gb = (gpart[0][1][lane] + gpart[1][1][lane]) + (gpart[2][1][lane] + gpart[3][1][lane]);
        f32x4 gx = (gpart[0][2][lane] + gpart[1][2][lane]) + (gpart[2][2][lane] + gpart[3][2][lane]);
        // symmetric: transposed store = same matrix
        *(f32x4*)(&Ga[l15 * 16 + q * 4]) = ga;
        *(f32x4*)(&Gb[l15 * 16 + q * 4]) = gb;
        #pragma unroll
        for (int r = 0; r < 4; ++r) Gxs[(q * 4 + r) * 16 + l15] = gx[r];
    }
    __syncthreads();

    const float eta   = 0.2f / (1.0f + expf(-eta_raw[0]));
    const float alpha = 0.5f + 0.5f / (1.0f + expf(-alpha_raw[0]));
    if (tid < 32) {                           // lanes 0-15: chunk a, 16-31: chunk b
        const float* G = (tid < 16) ? Ga : Gb;
        float gtt = G[l15 * 17];
        float n   = fmaxf(sqrtf(gtt), 1e-6f);
        float inv = 1.0f / n;
        csh[tid] = eta * (1.0f - inv) * inv / alpha;
    }
    __syncthreads();

    if (tid < 32) {                           // column-parallel forward substitution x2
        const int j = l15;
        const float* G  = (tid < 16) ? Ga : Gb;
        const float* cp = (tid < 16) ? csh : csh + 16;
        float cr[16];
        #pragma unroll
        for (int k = 0; k < 16; ++k) cr[k] = cp[k];
        float Tcol[16];
        Tcol[0] = 0.f;
        #pragma unroll
        for (int t = 1; t < 16; ++t) {
            float acc = cr[j] * G[t * 16 + j];
            #pragma unroll
            for (int k = 1; k < 15; ++k)
                if (k < t) acc += cr[k] * G[t * 16 + k] * Tcol[k];
            Tcol[t] = (t > j) ? acc : 0.f;
        }
        float* Tsj = Ts[tid >> 4];
        #pragma unroll
        for (int t = 0; t < 16; ++t) Tsj[t * 16 + j] = Tcol[t];
    }
    __syncthreads();

    if (tid < 64) {
        unsigned char* bp = blob + (size_t)(b * NP_ + p) * PBLOB_;
        const int idx = l15 * 16 + q * 4;
        *(bf16x4*)(bp + idx * 2)        = pk4(*(const f32x4*)(&Ts[0][idx]));
        *(bf16x4*)(bp + 512 + idx * 2)  = pk4(*(const f32x4*)(&Ts[1][idx]));
        *(bf16x4*)(bp + 1024 + idx * 2) = pk4(*(const f32x4*)(&Gxs[idx]));
        if (tid < 32) ((float*)(bp + 1536))[tid] = csh[tid];
    }
}

// ---------------- main scan: one 512-thread block (8 waves) per (batch, rowblk).
// Software-pipelined: pair j+1's retrieval is issued against the STALE master
// M_{j-1} in body(j)'s pre-barrier phase, together with on-the-fly cross-Grams
// X_{j+1}X_j^T (per-wave partial MFMAs). All six 16x16 sums go through
// conflict-free SoA ds_add_f32 into a 4-deep parity rotation. Post-barrier,
// bb_true = a32*(bb_stale + CrossA*ea_prev + CrossB*eb_prev); the only
// loop-carried chain is e_j -> 2 corr MFMAs -> Ta -> ea -> Gx -> Tb -> eb.
__global__ __launch_bounds__(512) void ldm_main(
    const float* __restrict__ x,
    const float* __restrict__ Minit,
    const float* __restrict__ alpha_raw,
    const unsigned char* __restrict__ blob,
    float* __restrict__ out)
{
    const int tid    = threadIdx.x;
    const int lane   = tid & 63;
    const int w      = __builtin_amdgcn_readfirstlane(tid >> 6); // 0..7
    const int batch  = blockIdx.x >> 4;
    const int rowblk = blockIdx.x & 15;
    const int l15    = lane & 15;
    const int q      = lane >> 4;
    const int kcol0  = w * 32 + q * 4;        // wave's column base (+16 for frag 1)

    // bufs[parity][quantity: bbA,bbB,CAA,CAB,CBA,CBB][comp][lane] (SoA, conflict-free)
    __shared__ float bufs[4][6][4][64];       // 24 KB
    float* lds = &bufs[0][0][0][0];

    const float alpha = 0.5f + 0.5f / (1.0f + expf(-alpha_raw[0]));
    const float a2 = alpha * alpha, a4 = a2 * a2, a8 = a4 * a4, a16 = a8 * a8;
    const float a32 = a16 * a16;
    const float inv_a32 = 1.0f / a32;
    const float aq = (q == 0) ? 1.f : (q == 1) ? a4 : (q == 2) ? a8 : a8 * a4;
    const f32x4 apowA = { aq, aq * alpha, aq * a2, aq * a2 * alpha };
    const f32x4 apowB = apowA * a16;

    // identity B-fragment for transpose MFMA
    const int s = l15 - (q << 2);
    bf16x4 IB;
    IB[0] = (s == 0) ? (short)0x3F80 : (short)0;
    IB[1] = (s == 1) ? (short)0x3F80 : (short)0;
    IB[2] = (s == 2) ? (short)0x3F80 : (short)0;
    IB[3] = (s == 3) ? (short)0x3F80 : (short)0;

    const int mrow = rowblk * 16 + l15;
    f32x4 master[2];
    master[0] = *(const f32x4*)(Minit + (size_t)mrow * D_ + kcol0);
    master[1] = *(const f32x4*)(Minit + (size_t)mrow * D_ + kcol0 + 16);

    const float* xb = x + (size_t)batch * S_ * D_;
    const unsigned char* bb0 = blob + (size_t)batch * NP_ * PBLOB_;
    float* outp = out + (size_t)batch * S_ * D_ + rowblk * 16 + l15;
    const int tfoff = (l15 * 16 + q * 4) * 2;

    struct Blob { bf16x4 Ta, Tb, Gx; f32x4 ca, cb; };
    Blob blobA, blobB;
    bf16x4 XA[4], XB[4];      // bf16 frags [a0,a1,b0,b1], cur/next alternating
    f32x4  Xf[4];             // f32 in-flight (enters body(j) holding X(j+1))
    bf16x4 ea_prev = {0,0,0,0}, eb_prev = {0,0,0,0};
    float* myadd = lds + lane;
    const f32x4 zz = {0,0,0,0};

    // ---------------- prologue
    for (int k = tid; k < 4 * 1536; k += 512) lds[k] = 0.f;
    __syncthreads();
    {
        const float* xp = xb + (size_t)l15 * D_ + kcol0;          // pair 0
        XA[0] = pk4(*(const f32x4*)(xp));
        XA[1] = pk4(*(const f32x4*)(xp + 16));
        XA[2] = pk4(*(const f32x4*)(xp + 16 * D_));
        XA[3] = pk4(*(const f32x4*)(xp + 16 * D_ + 16));
        const float* xq = xb + ((size_t)32 + l15) * D_ + kcol0;   // pair 1
        Xf[0] = *(const f32x4*)(xq);
        Xf[1] = *(const f32x4*)(xq + 16);
        Xf[2] = *(const f32x4*)(xq + 16 * D_);
        Xf[3] = *(const f32x4*)(xq + 16 * D_ + 16);
        blobA.Ta = *(const bf16x4*)(bb0 + tfoff);
        blobA.Tb = *(const bf16x4*)(bb0 + 512 + tfoff);
        blobA.Gx = *(const bf16x4*)(bb0 + 1024 + tfoff);
        blobA.ca = *(const f32x4*)(bb0 + 1536 + q * 16);
        blobA.cb = *(const f32x4*)(bb0 + 1600 + q * 16);
        // stale retrieval for pair 0 vs M_init; pre-divide by a32 so that the
        // uniform in-loop bb = a32*(stale+corr) reproduces bb_true exactly.
        bf16x4 m0b = pk4(master[0]), m1b = pk4(master[1]);
        f32x4 ra = mfma_bf16(XA[1], m1b, mfma_bf16(XA[0], m0b, zz));
        f32x4 rb = mfma_bf16(XA[3], m1b, mfma_bf16(XA[2], m0b, zz));
        ra *= inv_a32; rb *= inv_a32;
        #pragma unroll
        for (int r = 0; r < 4; ++r) {
            atomicAdd(myadd + 0 * 256 + r * 64, ra[r]);
            atomicAdd(myadd + 1 * 256 + r * 64, rb[r]);
        }
        // body(0)'s barrier covers these adds
    }

    auto body = [&](int j, bf16x4 (&Xc)[4], bf16x4 (&Xn)[4], Blob& bc, Blob& bn) {
        const int par = j & 3, ap = (j + 1) & 3, zp = (j + 2) & 3;
        // pk4 pending X(j+1)
        Xn[0] = pk4(Xf[0]); Xn[1] = pk4(Xf[1]); Xn[2] = pk4(Xf[2]); Xn[3] = pk4(Xf[3]);
        // prefetch X(j+2) and blob(j+1)
        int px = j + 2; if (px > NP_ - 1) px = NP_ - 1;
        int bx = j + 1; if (bx > NP_ - 1) bx = NP_ - 1;
        {
            const float* xp = xb + ((size_t)px * 32 + l15) * D_ + kcol0;
            Xf[0] = *(const f32x4*)(xp);
            Xf[1] = *(const f32x4*)(xp + 16);
            Xf[2] = *(const f32x4*)(xp + 16 * D_);
            Xf[3] = *(const f32x4*)(xp + 16 * D_ + 16);
            const unsigned char* bp = bb0 + (size_t)bx * PBLOB_;
            bn.Ta = *(const bf16x4*)(bp + tfoff);
            bn.Tb = *(const bf16x4*)(bp + 512 + tfoff);
            bn.Gx = *(const bf16x4*)(bp + 1024 + tfoff);
            bn.ca = *(const f32x4*)(bp + 1536 + q * 16);
            bn.cb = *(const f32x4*)(bp + 1600 + q * 16);
        }
        // stale retrieval partials for pair j+1 vs master (= M_{j-1} here)
        bf16x4 m0b = pk4(master[0]), m1b = pk4(master[1]);
        f32x4 ra = mfma_bf16(Xn[1], m1b, mfma_bf16(Xn[0], m0b, zz));
        f32x4 rb = mfma_bf16(Xn[3], m1b, mfma_bf16(Xn[2], m0b, zz));
        // cross-Gram partials (pair j) x (pair j+1); C-layout == A-frag of Cross
        f32x4 caa = mfma_bf16(Xc[1], Xn[1], mfma_bf16(Xc[0], Xn[0], zz));
        f32x4 cab = mfma_bf16(Xc[3], Xn[1], mfma_bf16(Xc[2], Xn[0], zz));
        f32x4 cba = mfma_bf16(Xc[1], Xn[3], mfma_bf16(Xc[0], Xn[2], zz));
        f32x4 cbb = mfma_bf16(Xc[3], Xn[3], mfma_bf16(Xc[2], Xn[2], zz));
        // transpose frags for pair j (X^T, own cols)
        bf16x4 t0a = pk4(mfma_bf16(Xc[0], IB, zz));
        bf16x4 t1a = pk4(mfma_bf16(Xc[1], IB, zz));
        bf16x4 t0b = pk4(mfma_bf16(Xc[2], IB, zz));
        bf16x4 t1b = pk4(mfma_bf16(Xc[3], IB, zz));
        // conflict-free SoA ds_add into buf[ap]
        float* ab = myadd + ap * 1536;
        #pragma unroll
        for (int r = 0; r < 4; ++r) {
            atomicAdd(ab + 0 * 256 + r * 64, ra[r]);
            atomicAdd(ab + 1 * 256 + r * 64, rb[r]);
            atomicAdd(ab + 2 * 256 + r * 64, caa[r]);
            atomicAdd(ab + 3 * 256 + r * 64, cab[r]);
            atomicAdd(ab + 4 * 256 + r * 64, cba[r]);
            atomicAdd(ab + 5 * 256 + r * 64, cbb[r]);
        }
        // zero buf[zp] (last read two barriers ago; next adds one barrier ahead)
        {
            float* zb = lds + zp * 1536;
            zb[tid] = 0.f; zb[tid + 512] = 0.f; zb[tid + 1024] = 0.f;
        }
        __syncthreads();
        // read pair j's six sums (added during body(j-1), complete since then)
        const float* rd = lds + par * 1536 + lane;
        f32x4 bbA, bbB, SAA, SAB, SBA, SBB;
        #pragma unroll
        for (int r = 0; r < 4; ++r) {
            bbA[r] = rd[0 * 256 + r * 64];
            bbB[r] = rd[1 * 256 + r * 64];
            SAA[r] = rd[2 * 256 + r * 64];
            SAB[r] = rd[3 * 256 + r * 64];
            SBA[r] = rd[4 * 256 + r * 64];
            SBB[r] = rd[5 * 256 + r * 64];
        }
        bf16x4 FAA = pk4(SAA), FAB = pk4(SAB), FBA = pk4(SBA), FBB = pk4(SBB);
        // bb_true = a32 * (stale + Cross_a*ea_prev + Cross_b*eb_prev)
        bbA = mfma_bf16(FAA, ea_prev, bbA);
        bbA = mfma_bf16(FAB, eb_prev, bbA);
        bbA *= a32;
        bbB = mfma_bf16(FBA, ea_prev, bbB);
        bbB = mfma_bf16(FBB, eb_prev, bbB);
        bbB *= a32;
        // chunk a fixup: d_a = (I+T_a)*bb_a
        f32x4 da = mfma_bf16(bc.Ta, pk4(bbA), bbA);
        if (w == 0) {
            #pragma unroll
            for (int r = 0; r < 4; ++r)
                outp[(size_t)(j * 32 + q * 4 + r) * D_] = da[r] * apowA[r];
        }
        bf16x4 ea = pk4(da * bc.ca);
        // chunk b in-pair correction + fixup
        bbB = mfma_bf16(bc.Gx, ea, bbB);
        f32x4 db = mfma_bf16(bc.Tb, pk4(bbB), bbB);
        if (w == 1) {
            #pragma unroll
            for (int r = 0; r < 4; ++r)
                outp[(size_t)(j * 32 + 16 + q * 4 + r) * D_] = db[r] * apowB[r];
        }
        bf16x4 eb = pk4(db * bc.cb);
        // master += X_a^T E_a + X_b^T E_b, then *alpha^32
        master[0] = mfma_bf16(t0a, ea, master[0]);
        master[0] = mfma_bf16(t0b, eb, master[0]) * a32;
        master[1] = mfma_bf16(t1a, ea, master[1]);
        master[1] = mfma_bf16(t1b, eb, master[1]) * a32;
        ea_prev = ea; eb_prev = eb;
    };

    for (int j = 0; j < NP_; j += 2) {
        body(j,     XA, XB, blobA, blobB);
        body(j + 1, XB, XA, blobB, blobA);
    }

    // M_final -> second output region [B, D, D]
    float* Mout = out + (size_t)B_ * S_ * D_
                + ((size_t)batch * D_ + mrow) * D_;
    *(f32x4*)(Mout + kcol0)      = master[0];
    *(f32x4*)(Mout + kcol0 + 16) = master[1];
}

extern "C" void kernel_launch(void* const* d_in, const int* in_sizes, int n_in,
                              void* d_out, int out_size, void* d_ws, size_t ws_size,
                              hipStream_t stream) {
    const float* x         = (const float*)d_in[0];
    const float* Minit     = (const float*)d_in[1];
    const float* eta_raw   = (const float*)d_in[2];
    const float* alpha_raw = (const float*)d_in[3];
    float* out = (float*)d_out;
    unsigned char* blob = (unsigned char*)d_ws;   // B_*NP_*1664 = 3.4 MB

    hipLaunchKernelGGL(ldm_prep, dim3(B_ * NP_), dim3(256), 0, stream,
                       x, eta_raw, alpha_raw, blob);
    hipLaunchKernelGGL(ldm_main, dim3(B_ * 16), dim3(512), 0, stream,
                       x, Minit, alpha_raw, blob, out);
}

// Round 3
// 274.528 us; speedup vs baseline: 8.0109x; 8.0109x over previous
//
#include <hip/hip_runtime.h>
#include <hip/hip_bf16.h>
#include <math.h>

typedef float  f32x4  __attribute__((ext_vector_type(4)));
typedef short  bf16x4 __attribute__((ext_vector_type(4)));
typedef __bf16 bfv4   __attribute__((ext_vector_type(4)));

#define B_    16
#define S_    4096
#define D_    256
#define CK_   16                 // chunk length
#define NC_   (S_ / CK_)         // 256 chunks
#define NP_   (NC_ / 2)          // 128 fused pairs (32-row superchunks)
#define PBLOB_ 1664              // 512 Ta + 512 Tb + 512 Gx (bf16) + 64 ca + 64 cb (f32)
#define W_    8                  // waves per main block (column split)

// ---------------- helpers
__device__ __forceinline__ f32x4 mfma_bf16(bf16x4 a, bf16x4 b, f32x4 c) {
#if defined(__has_builtin) && __has_builtin(__builtin_amdgcn_mfma_f32_16x16x16bf16_1k)
    return __builtin_amdgcn_mfma_f32_16x16x16bf16_1k(a, b, c, 0, 0, 0);
#else
    f32x4 d;
    asm("v_mfma_f32_16x16x16_bf16 %0, %1, %2, %3" : "=v"(d) : "v"(a), "v"(b), "v"(c));
    return d;
#endif
}
__device__ __forceinline__ bf16x4 pk4(f32x4 v) {
    bfv4 h;
    h[0] = (__bf16)v[0]; h[1] = (__bf16)v[1]; h[2] = (__bf16)v[2]; h[3] = (__bf16)v[3];
    return __builtin_bit_cast(bf16x4, h);
}
__device__ __forceinline__ f32x4 up4(bf16x4 h) {
    f32x4 r;
    r[0] = __uint_as_float(((unsigned)(unsigned short)h[0]) << 16);
    r[1] = __uint_as_float(((unsigned)(unsigned short)h[1]) << 16);
    r[2] = __uint_as_float(((unsigned)(unsigned short)h[2]) << 16);
    r[3] = __uint_as_float(((unsigned)(unsigned short)h[3]) << 16);
    return r;
}

// ---------------- prepass: one 64-thread wave per (b, pair). (R1-verified version)
__global__ __launch_bounds__(64) void ldm_prep(
    const float* __restrict__ x,
    const float* __restrict__ eta_raw,
    const float* __restrict__ alpha_raw,
    unsigned char* __restrict__ blob)
{
    const int lane = threadIdx.x;
    const int b = blockIdx.x >> 7;            // NP_ = 128
    const int p = blockIdx.x & (NP_ - 1);
    const int l15 = lane & 15;
    const int q   = lane >> 4;

    __shared__ float Ga[256], Gb[256], Gxs[256];
    __shared__ float csh[32];
    __shared__ float Ts[2][256];

    // A-fragments: lane holds row t=l15, cols kb*16 + q*4 + {0..3}
    const float* xa = x + ((size_t)b * S_ + (size_t)p * 32 + l15) * D_ + q * 4;
    const float* xc = xa + 16 * D_;           // chunk b rows

    const f32x4 z = {0,0,0,0};
    f32x4 ga1=z, ga2=z, ga3=z, gb1=z, gb2=z, gb3=z, gx1=z, gx2=z, gx3=z;
    #pragma unroll 4
    for (int kb = 0; kb < 16; ++kb) {
        f32x4 va = *(const f32x4*)(xa + kb * 16);
        f32x4 vb = *(const f32x4*)(xc + kb * 16);
        bf16x4 ha = pk4(va), la = pk4(va - up4(ha));
        bf16x4 hb = pk4(vb), lb = pk4(vb - up4(hb));
        ga1 = mfma_bf16(ha, ha, ga1);
        ga2 = mfma_bf16(ha, la, ga2);
        ga3 = mfma_bf16(la, ha, ga3);
        gb1 = mfma_bf16(hb, hb, gb1);
        gb2 = mfma_bf16(hb, lb, gb2);
        gb3 = mfma_bf16(lb, hb, gb3);
        gx1 = mfma_bf16(hb, ha, gx1);         // Gx[t_b][t_a] = x_b . x_a
        gx2 = mfma_bf16(hb, la, gx2);
        gx3 = mfma_bf16(lb, ha, gx3);
    }
    f32x4 ga = (ga1 + ga2) + ga3;             // C layout: lane holds G[q*4+r][l15]
    f32x4 gb = (gb1 + gb2) + gb3;
    f32x4 gx = (gx1 + gx2) + gx3;
    // symmetric: transposed store = same matrix, contiguous b128 per lane
    *(f32x4*)(&Ga[l15 * 16 + q * 4]) = ga;
    *(f32x4*)(&Gb[l15 * 16 + q * 4]) = gb;
    // Gx not symmetric: true transpose via scatter -> Gxs[t_b*16 + t_a]
    #pragma unroll
    for (int r = 0; r < 4; ++r) Gxs[(q * 4 + r) * 16 + l15] = gx[r];
    __syncthreads();

    const float eta   = 0.2f / (1.0f + expf(-eta_raw[0]));
    const float alpha = 0.5f + 0.5f / (1.0f + expf(-alpha_raw[0]));
    if (lane < 32) {                          // lanes 0-15: chunk a, 16-31: chunk b
        const float* G = (lane < 16) ? Ga : Gb;
        float gtt = G[l15 * 17];
        float n   = fmaxf(sqrtf(gtt), 1e-6f);
        float inv = 1.0f / n;
        csh[lane] = eta * (1.0f - inv) * inv / alpha;
    }
    __syncthreads();

    if (lane < 32) {                          // column-parallel forward substitution x2
        const int j = l15;
        const float* G  = (lane < 16) ? Ga : Gb;
        const float* cp = (lane < 16) ? csh : csh + 16;
        float cr[16];
        #pragma unroll
        for (int k = 0; k < 16; ++k) cr[k] = cp[k];
        float Tcol[16];
        Tcol[0] = 0.f;
        #pragma unroll
        for (int t = 1; t < 16; ++t) {
            float acc = cr[j] * G[t * 16 + j];
            #pragma unroll
            for (int k = 1; k < 15; ++k)
                if (k < t) acc += cr[k] * G[t * 16 + k] * Tcol[k];
            Tcol[t] = (t > j) ? acc : 0.f;
        }
        float* Tsj = Ts[lane >> 4];
        #pragma unroll
        for (int t = 0; t < 16; ++t) Tsj[t * 16 + j] = Tcol[t];
    }
    __syncthreads();

    unsigned char* bp = blob + (size_t)(b * NP_ + p) * PBLOB_;
    const int idx = l15 * 16 + q * 4;
    *(bf16x4*)(bp + idx * 2)        = pk4(*(const f32x4*)(&Ts[0][idx]));
    *(bf16x4*)(bp + 512 + idx * 2)  = pk4(*(const f32x4*)(&Ts[1][idx]));
    *(bf16x4*)(bp + 1024 + idx * 2) = pk4(*(const f32x4*)(&Gxs[idx]));
    if (lane < 32) ((float*)(bp + 1536))[lane] = csh[lane];
}

// ---------------- main scan: one 512-thread block (8 waves) per (batch, rowblk).
// R1 pair-fused algebra, but the 8-way cross-wave reduction is 3-stage:
//   stage 1: each wave ds_writes its 2 partials (16 KB)
//   stage 2: waves 0-1 alone sum the 8 partials (16 KB read + 2 KB write)
//            while waves 2-7 compute transpose fragments in the shadow
//   stage 3: all waves read the 2 final sums (16 KB broadcast)
// 50 KB LDS traffic per body vs R1's 144 KB (every wave read all 8 partials).
__global__ __launch_bounds__(512) void ldm_main(
    const float* __restrict__ x,
    const float* __restrict__ Minit,
    const float* __restrict__ alpha_raw,
    const unsigned char* __restrict__ blob,
    float* __restrict__ out)
{
    const int tid    = threadIdx.x;
    const int lane   = tid & 63;
    const int w      = __builtin_amdgcn_readfirstlane(tid >> 6); // 0..7
    const int batch  = blockIdx.x >> 4;
    const int rowblk = blockIdx.x & 15;
    const int l15    = lane & 15;
    const int q      = lane >> 4;
    const int kcol0  = w * 32 + q * 4;        // wave's column base (+16 for frag 1)

    __shared__ f32x4 red[2][W_][64];          // [qty: a,b][wave][lane] = 16 KB
    __shared__ f32x4 fsum[2][64];             // final sums, 2 KB

    const float alpha = 0.5f + 0.5f / (1.0f + expf(-alpha_raw[0]));
    const float a2 = alpha * alpha, a4 = a2 * a2, a8 = a4 * a4, a16 = a8 * a8;
    const float a32 = a16 * a16;
    const float aq = (q == 0) ? 1.f : (q == 1) ? a4 : (q == 2) ? a8 : a8 * a4;
    const f32x4 apowA = { aq, aq * alpha, aq * a2, aq * a2 * alpha };
    const f32x4 apowB = apowA * a16;

    // identity B-fragment for transpose MFMA
    const int s = l15 - (q << 2);
    bf16x4 IB;
    IB[0] = (s == 0) ? (short)0x3F80 : (short)0;
    IB[1] = (s == 1) ? (short)0x3F80 : (short)0;
    IB[2] = (s == 2) ? (short)0x3F80 : (short)0;
    IB[3] = (s == 3) ? (short)0x3F80 : (short)0;

    const int mrow = rowblk * 16 + l15;
    f32x4 master[2];
    master[0] = *(const f32x4*)(Minit + (size_t)mrow * D_ + kcol0);
    master[1] = *(const f32x4*)(Minit + (size_t)mrow * D_ + kcol0 + 16);

    const float* xb = x + (size_t)batch * S_ * D_;
    const unsigned char* bb0 = blob + (size_t)batch * NP_ * PBLOB_;
    float* outp = out + (size_t)batch * S_ * D_ + rowblk * 16 + l15;
    const int tfoff = (l15 * 16 + q * 4) * 2;

    struct PairBuf {
        f32x4  Xa[2], Xb[2];
        bf16x4 Ta, Tb, Gx;
        f32x4  ca, cb;
    };
    PairBuf Abuf, Bbuf;

    {   // preload pair 0
        const float* xp = xb + (size_t)l15 * D_ + kcol0;
        Abuf.Xa[0] = *(const f32x4*)(xp);
        Abuf.Xa[1] = *(const f32x4*)(xp + 16);
        Abuf.Xb[0] = *(const f32x4*)(xp + 16 * D_);
        Abuf.Xb[1] = *(const f32x4*)(xp + 16 * D_ + 16);
        Abuf.Ta = *(const bf16x4*)(bb0 + tfoff);
        Abuf.Tb = *(const bf16x4*)(bb0 + 512 + tfoff);
        Abuf.Gx = *(const bf16x4*)(bb0 + 1024 + tfoff);
        Abuf.ca = *(const f32x4*)(bb0 + 1536 + q * 16);
        Abuf.cb = *(const f32x4*)(bb0 + 1600 + q * 16);
    }

    auto body = [&](int p, PairBuf& cur, PairBuf& nxt) {
        int px = p + 1; if (px > NP_ - 1) px = NP_ - 1;
        {   // prefetch pair p+1 (loads in flight across the whole body)
            const float* xp = xb + ((size_t)px * 32 + l15) * D_ + kcol0;
            nxt.Xa[0] = *(const f32x4*)(xp);
            nxt.Xa[1] = *(const f32x4*)(xp + 16);
            nxt.Xb[0] = *(const f32x4*)(xp + 16 * D_);
            nxt.Xb[1] = *(const f32x4*)(xp + 16 * D_ + 16);
            const unsigned char* bp = bb0 + (size_t)px * PBLOB_;
            nxt.Ta = *(const bf16x4*)(bp + tfoff);
            nxt.Tb = *(const bf16x4*)(bp + 512 + tfoff);
            nxt.Gx = *(const bf16x4*)(bp + 1024 + tfoff);
            nxt.ca = *(const f32x4*)(bp + 1536 + q * 16);
            nxt.cb = *(const f32x4*)(bp + 1600 + q * 16);
        }
        bf16x4 m0 = pk4(master[0]), m1 = pk4(master[1]);
        bf16x4 a0 = pk4(cur.Xa[0]), a1 = pk4(cur.Xa[1]);
        bf16x4 b0 = pk4(cur.Xb[0]), b1 = pk4(cur.Xb[1]);
        const f32x4 zz = {0,0,0,0};
        f32x4 acca = mfma_bf16(a0, m0, zz);
        acca = mfma_bf16(a1, m1, acca);
        f32x4 accb = mfma_bf16(b0, m0, zz);
        accb = mfma_bf16(b1, m1, accb);
        red[0][w][lane] = acca;               // stage 1: partials
        red[1][w][lane] = accb;
        __syncthreads();                      // B1: partials visible

        // stage 2: waves 0-1 reduce; waves 2-7 overlap transpose frags
        if (tid < 128) {
            const int qy = tid >> 6, ln = tid & 63;
            f32x4 u0 = red[qy][0][ln] + red[qy][1][ln];
            f32x4 u1 = red[qy][2][ln] + red[qy][3][ln];
            f32x4 u2 = red[qy][4][ln] + red[qy][5][ln];
            f32x4 u3 = red[qy][6][ln] + red[qy][7][ln];
            fsum[qy][ln] = (u0 + u1) + (u2 + u3);
        }
        // X^T fragments (own cols)
        f32x4 t0a = mfma_bf16(a0, IB, zz);
        f32x4 t1a = mfma_bf16(a1, IB, zz);
        f32x4 t0b = mfma_bf16(b0, IB, zz);
        f32x4 t1b = mfma_bf16(b1, IB, zz);
        __syncthreads();                      // B2: sums visible

        // stage 3: broadcast read
        f32x4 bba = fsum[0][lane];
        f32x4 bbb = fsum[1][lane];

        // chunk a fixup: d_a = (I+T_a) * bb_a
        f32x4 da = mfma_bf16(cur.Ta, pk4(bba), bba);
        if (w == 0) {
            #pragma unroll
            for (int r = 0; r < 4; ++r)
                outp[(size_t)(p * 32 + q * 4 + r) * D_] = da[r] * apowA[r];
        }
        bf16x4 ea = pk4(da * cur.ca);
        // chunk b cross-correction + fixup
        f32x4 bbc = mfma_bf16(cur.Gx, ea, bbb);
        f32x4 db = mfma_bf16(cur.Tb, pk4(bbc), bbc);
        if (w == 1) {
            #pragma unroll
            for (int r = 0; r < 4; ++r)
                outp[(size_t)(p * 32 + 16 + q * 4 + r) * D_] = db[r] * apowB[r];
        }
        bf16x4 eb = pk4(db * cur.cb);
        // master += X_a^T E_a + X_b^T E_b, then *alpha^32
        master[0] = mfma_bf16(pk4(t0a), ea, master[0]);
        master[0] = mfma_bf16(pk4(t0b), eb, master[0]) * a32;
        master[1] = mfma_bf16(pk4(t1a), ea, master[1]);
        master[1] = mfma_bf16(pk4(t1b), eb, master[1]) * a32;
    };

    for (int p = 0; p < NP_; p += 2) {
        body(p,     Abuf, Bbuf);
        body(p + 1, Bbuf, Abuf);
    }

    // M_final -> second output region [B, D, D]
    float* Mout = out + (size_t)B_ * S_ * D_
                + ((size_t)batch * D_ + mrow) * D_;
    *(f32x4*)(Mout + kcol0)      = master[0];
    *(f32x4*)(Mout + kcol0 + 16) = master[1];
}

extern "C" void kernel_launch(void* const* d_in, const int* in_sizes, int n_in,
                              void* d_out, int out_size, void* d_ws, size_t ws_size,
                              hipStream_t stream) {
    const float* x         = (const float*)d_in[0];
    const float* Minit     = (const float*)d_in[1];
    const float* eta_raw   = (const float*)d_in[2];
    const float* alpha_raw = (const float*)d_in[3];
    float* out = (float*)d_out;
    unsigned char* blob = (unsigned char*)d_ws;   // B_*NP_*1664 = 3.4 MB

    hipLaunchKernelGGL(ldm_prep, dim3(B_ * NP_), dim3(64), 0, stream,
                       x, eta_raw, alpha_raw, blob);
    hipLaunchKernelGGL(ldm_main, dim3(B_ * 16), dim3(512), 0, stream,
                       x, Minit, alpha_raw, blob, out);
}